// Round 3
// baseline (1204.602 us; speedup 1.0000x reference)
//
#include <hip/hip_runtime.h>
#include <hip/hip_bf16.h>

#define K_TOT 4096
#define N_TOT 11008
#define LDP 72   // padded LDS row length in elements (144B stride: 2-way banks = free)

typedef __bf16 bf16x8 __attribute__((ext_vector_type(8)));
typedef float  f32x4  __attribute__((ext_vector_type(4)));
typedef float  f32x8  __attribute__((ext_vector_type(8)));

// C = X[M,K] * W[N,K]^T + bias ; W dequantized inline from packed int4.
// Harness schema promotes fp16 -> float32: all float I/O is f32.
__global__ __launch_bounds__(256)
void qgemm_fused(const float* __restrict__ X,
                 const int*   __restrict__ Qw,
                 const float* __restrict__ Sc,
                 const float* __restrict__ Zr,
                 const float* __restrict__ Bias,
                 float*       __restrict__ C)
{
    __shared__ __bf16 As[128][LDP];   // [m 128][k 64 + pad]
    __shared__ __bf16 Bs[128][LDP];   // [n 128][k 64 + pad]

    const int tid  = threadIdx.x;
    const int lane = tid & 63;
    const int wid  = tid >> 6;
    const int l15  = lane & 15;
    const int lhi  = lane >> 4;

    const int bm0 = blockIdx.x * 128;
    const int bn0 = blockIdx.y * 128;
    const int wm  = (wid >> 1) * 64;
    const int wn  = (wid & 1) * 64;

    // ---- A staging: thread -> (row ar + 32p, col unit tid&7), 8 f32 each, 4 passes
    const int ar = tid >> 3;          // 0..31
    const int ac = (tid & 7) * 8;     // element col 0..56

    // ---- B staging: thread -> (row nl, half h); 8 packed words -> 32 contiguous k
    const int nl   = tid >> 1;        // 0..127
    const int half = tid & 1;
    const int n_g  = bn0 + nl;
    const int* qptr = Qw + (size_t)(n_g >> 2) * K_TOT + (nl & 3) * 16 + half * 8;
    const float* scp = Sc + n_g;
    const float* zrp = Zr + n_g;

    f32x4 acc[4][4] = {};

    for (int kt = 0; kt < K_TOT / 64; ++kt) {
        const int k0 = kt * 64;

        // global loads
        const int4 wa = *(const int4*)(qptr + k0);
        const int4 wb = *(const int4*)(qptr + k0 + 4);
        const float s = scp[(size_t)(kt >> 1) * N_TOT];
        const float z = zrp[(size_t)(kt >> 1) * N_TOT];

        f32x8 av[4];
        #pragma unroll
        for (int p = 0; p < 4; ++p)
            av[p] = *(const f32x8*)(X + (size_t)(bm0 + p * 32 + ar) * K_TOT + k0 + ac);

        // dequant: nibble i of word uu -> k_local = half*32 + i*8 + uu
        const int w8[8] = {wa.x, wa.y, wa.z, wa.w, wb.x, wb.y, wb.z, wb.w};
        bf16x8 ov[4];
        #pragma unroll
        for (int uu = 0; uu < 8; ++uu) {
            const unsigned v = (unsigned)w8[uu] & 0xFFFFu;
            #pragma unroll
            for (int i = 0; i < 4; ++i) {
                ov[i][uu] = (__bf16)fmaf((float)((v >> (4 * i)) & 0xFu), s, z);
            }
        }

        // LDS writes (padded rows, no swizzle)
        #pragma unroll
        for (int p = 0; p < 4; ++p) {
            bf16x8 ab;
            #pragma unroll
            for (int j = 0; j < 8; ++j) ab[j] = (__bf16)av[p][j];
            *(bf16x8*)&As[p * 32 + ar][ac] = ab;
        }
        #pragma unroll
        for (int cc = 0; cc < 4; ++cc)
            *(bf16x8*)&Bs[nl][half * 32 + cc * 8] = ov[cc];

        __syncthreads();

        #pragma unroll
        for (int ks = 0; ks < 2; ++ks) {
            bf16x8 af[4], bfr[4];
            const int kc = ks * 32 + lhi * 8;
            #pragma unroll
            for (int mi = 0; mi < 4; ++mi)
                af[mi] = *(const bf16x8*)&As[wm + mi * 16 + l15][kc];
            #pragma unroll
            for (int ni = 0; ni < 4; ++ni)
                bfr[ni] = *(const bf16x8*)&Bs[wn + ni * 16 + l15][kc];
            #pragma unroll
            for (int mi = 0; mi < 4; ++mi)
                #pragma unroll
                for (int ni = 0; ni < 4; ++ni)
                    acc[mi][ni] = __builtin_amdgcn_mfma_f32_16x16x32_bf16(
                        af[mi], bfr[ni], acc[mi][ni], 0, 0, 0);
        }

        __syncthreads();
    }

    // epilogue: C/D layout col=lane&15, row=(lane>>4)*4+reg (m89-verified)
    #pragma unroll
    for (int ni = 0; ni < 4; ++ni) {
        const int col = bn0 + wn + ni * 16 + l15;
        const float bv = Bias[col];
        #pragma unroll
        for (int mi = 0; mi < 4; ++mi) {
            const int row = bm0 + wm + mi * 16 + lhi * 4;
            #pragma unroll
            for (int r = 0; r < 4; ++r) {
                C[(size_t)(row + r) * N_TOT + col] = acc[mi][ni][r] + bv;
            }
        }
    }
}

extern "C" void kernel_launch(void* const* d_in, const int* in_sizes, int n_in,
                              void* d_out, int out_size, void* d_ws, size_t ws_size,
                              hipStream_t stream) {
    const float* X    = (const float*)d_in[0];
    const int*   Qw   = (const int*)d_in[1];
    const float* Sc   = (const float*)d_in[2];
    const float* Zr   = (const float*)d_in[3];
    const float* Bias = (const float*)d_in[4];
    float* C = (float*)d_out;

    const int M = in_sizes[0] / K_TOT;          // 8192
    dim3 grid(M / 128, N_TOT / 128);            // (64, 86)
    qgemm_fused<<<grid, dim3(256), 0, stream>>>(X, Qw, Sc, Zr, Bias, C);
}